// Round 4
// baseline (15606.082 us; speedup 1.0000x reference)
//
#include <hip/hip_runtime.h>
#include <hip/hip_bf16.h>
#include <cstdint>
#include <cstddef>

// Problem dims
constexpr int Bz = 128, Tz = 25, Ez = 512, Hz = 1024, Vz = 10000, Fz = 2048;

__device__ __forceinline__ float sigm(float x) { return 1.f / (1.f + __expf(-x)); }
__device__ __forceinline__ float tanh_f(float x) {
    float e = __expf(-2.f * x);
    return 2.f / (1.f + e) - 1.f;
}
__device__ __forceinline__ float bf2f(unsigned short u) {
    return __builtin_bit_cast(float, ((unsigned)u) << 16);
}

// ---------------- dtype detector (bf16=1 / f32=0), from embedding halfwords ----
__global__ __launch_bounds__(256) void detect_k(const unsigned short* __restrict__ raw,
                                                int* __restrict__ flag) {
    __shared__ int sbuf[256];
    int tid = threadIdx.x, cnt = 0;
    for (int i = tid; i < 1024; i += 256) {
        unsigned short u = raw[2 * i];
        int e = (u >> 7) & 0xff;
        if (e >= 110 && e <= 127) cnt++;
    }
    sbuf[tid] = cnt;
    __syncthreads();
    for (int s = 128; s > 0; s >>= 1) {
        if (tid < s) sbuf[tid] += sbuf[tid + s];
        __syncthreads();
    }
    if (tid == 0) flag[0] = (sbuf[0] >= 512) ? 1 : 0;
}

__device__ __forceinline__ float ldf(const void* p, size_t i, int isbf) {
    return isbf ? bf2f(((const unsigned short*)p)[i]) : ((const float*)p)[i];
}

// ---------------- embedding gather -> f32 X0[t*128+b][e] ----------------
__global__ __launch_bounds__(256) void gatherf_k(const int* __restrict__ tok,
                                                 const void* __restrict__ emb,
                                                 float* __restrict__ X0,
                                                 const int* __restrict__ flag) {
    int idx = blockIdx.x * 256 + threadIdx.x;   // 3200*128 groups of 4
    if (idx >= 3200 * (Ez / 4)) return;
    int r = idx >> 7, c4 = (idx & 127) << 2;
    int t = r >> 7, b = r & 127;
    int tk = tok[b * Tz + t];
    int isbf = *flag;
    float4 o;
    o.x = ldf(emb, (size_t)tk * Ez + c4 + 0, isbf);
    o.y = ldf(emb, (size_t)tk * Ez + c4 + 1, isbf);
    o.z = ldf(emb, (size_t)tk * Ez + c4 + 2, isbf);
    o.w = ldf(emb, (size_t)tk * Ez + c4 + 3, isbf);
    *(float4*)(X0 + (size_t)r * Ez + c4) = o;
}

// ---------------- features -> f32 ----------------
__global__ __launch_bounds__(256) void convf_k(const void* __restrict__ in,
                                               float* __restrict__ out, int n,
                                               const int* __restrict__ flag) {
    int idx = blockIdx.x * 256 + threadIdx.x;
    if (idx >= n) return;
    out[idx] = ldf(in, idx, *flag);
}

// ---------------- bias pack to f32 ----------------
__global__ __launch_bounds__(256) void pack2_k(
    const void* __restrict__ bp,
    const void* __restrict__ bf0, const void* __restrict__ bi0,
    const void* __restrict__ bo0, const void* __restrict__ bg0,
    const void* __restrict__ bf1, const void* __restrict__ bi1,
    const void* __restrict__ bo1, const void* __restrict__ bg1,
    const void* __restrict__ bout,
    float* __restrict__ bp_f, float* __restrict__ b0_f, float* __restrict__ b1_f,
    float* __restrict__ bout_f, const int* __restrict__ flag) {
    int idx = blockIdx.x * 256 + threadIdx.x;
    int isbf = *flag;
    if (idx < 1024) {
        bp_f[idx] = ldf(bp, idx, isbf);
    } else if (idx < 5120) {
        int n = idx - 1024, g = n >> 10, j = n & 1023;
        const void* s = (g == 0) ? bf0 : (g == 1) ? bi0 : (g == 2) ? bo0 : bg0;
        b0_f[n] = ldf(s, j, isbf);
    } else if (idx < 9216) {
        int n = idx - 5120, g = n >> 10, j = n & 1023;
        const void* s = (g == 0) ? bf1 : (g == 1) ? bi1 : (g == 2) ? bo1 : bg1;
        b1_f[n] = ldf(s, j, isbf);
    } else if (idx < 9216 + Vz) {
        int n = idx - 9216;
        bout_f[n] = ldf(bout, n, isbf);
    }
}

// ---------------- LSTM cell elementwise (all f32) ----------------
// gates [128][4096], col = gate*1024 + j, gate order f,i,o,g
__global__ __launch_bounds__(256) void cellf_k(const float* __restrict__ gates,
                                               float* __restrict__ c,
                                               float* __restrict__ d1, int ld1,
                                               float* __restrict__ d2, int ld2) {
    int idx = blockIdx.x * 256 + threadIdx.x;   // 131072
    int m = idx >> 10, j = idx & 1023;
    const float* g = gates + (size_t)m * 4096 + j;
    float fg = sigm(g[0]);
    float ig = sigm(g[1024]);
    float og = sigm(g[2048]);
    float gg = tanh_f(g[3072]);
    float cn = fg * c[idx] + ig * gg;
    c[idx] = cn;
    float h = og * tanh_f(cn);
    d1[(size_t)m * ld1 + j] = h;
    d2[(size_t)m * ld2 + j] = h;
}

// ---------------- correct-by-construction tiled VALU SGEMM ----------------
// C[M,N] = A[M,K] @ B[rowoff : rowoff+K, :N] (+ addv). A is f32 [M][lda].
// B is the ORIGINAL weight buffer, layout [Ktot][ldb], dtype per flag.
// MULTI: global col n -> (matrix n>>10, col n&1023), each with ldb.
// STORE: 0 = f32 to Cout[grow*ldc+gcol];  2 = f32 logits-permuted
//        (row = t*128+b -> out[b][t][gcol]).  ACT: 1 = leaky_relu(0.01).
// M must be a multiple of 64.
template <int STORE, int ACT, bool MULTI>
__global__ __launch_bounds__(256) void sgemm_k(
    const float* __restrict__ A, int lda,
    const void* __restrict__ B0, const void* __restrict__ B1,
    const void* __restrict__ B2, const void* __restrict__ B3,
    int ldb, int rowoff,
    const float* __restrict__ addv, int astride, int amask,
    void* __restrict__ Cout, int ldc, int M, int N, int K,
    const int* __restrict__ flag) {
    __shared__ float As[64][17];
    __shared__ float Bs[16][68];
    const int tid = threadIdx.x;
    const int tx = tid & 15, ty = tid >> 4;
    const int bn0 = blockIdx.x * 64, bm0 = blockIdx.y * 64;
    const int isbf = *flag;

    float acc[4][4];
#pragma unroll
    for (int i = 0; i < 4; i++)
#pragma unroll
        for (int j = 0; j < 4; j++) acc[i][j] = 0.f;

    for (int kt = 0; kt < K; kt += 16) {
        // A tile 64x16 (M is a multiple of 64 -> no row guard)
        for (int i = tid; i < 1024; i += 256) {
            int r = i >> 4, cc = i & 15;
            As[r][cc] = A[(size_t)(bm0 + r) * lda + kt + cc];
        }
        // B tile 16x64, natural [K][N] layout, coalesced along n
        for (int i = tid; i < 1024; i += 256) {
            int kk = i >> 6, n = i & 63;
            int ng = bn0 + n;
            float v = 0.f;
            if (ng < N) {
                const void* bptr;
                int col;
                if constexpr (MULTI) {
                    int pi = ng >> 10;
                    bptr = (pi == 0) ? B0 : (pi == 1) ? B1 : (pi == 2) ? B2 : B3;
                    col = ng & 1023;
                } else {
                    bptr = B0;
                    col = ng;
                }
                v = ldf(bptr, (size_t)(rowoff + kt + kk) * ldb + col, isbf);
            }
            Bs[kk][n] = v;
        }
        __syncthreads();

#pragma unroll
        for (int kk = 0; kk < 16; kk++) {
            float a0 = As[ty * 4 + 0][kk];
            float a1 = As[ty * 4 + 1][kk];
            float a2 = As[ty * 4 + 2][kk];
            float a3 = As[ty * 4 + 3][kk];
            float4 b = *(const float4*)&Bs[kk][tx * 4];
            acc[0][0] = fmaf(a0, b.x, acc[0][0]);
            acc[0][1] = fmaf(a0, b.y, acc[0][1]);
            acc[0][2] = fmaf(a0, b.z, acc[0][2]);
            acc[0][3] = fmaf(a0, b.w, acc[0][3]);
            acc[1][0] = fmaf(a1, b.x, acc[1][0]);
            acc[1][1] = fmaf(a1, b.y, acc[1][1]);
            acc[1][2] = fmaf(a1, b.z, acc[1][2]);
            acc[1][3] = fmaf(a1, b.w, acc[1][3]);
            acc[2][0] = fmaf(a2, b.x, acc[2][0]);
            acc[2][1] = fmaf(a2, b.y, acc[2][1]);
            acc[2][2] = fmaf(a2, b.z, acc[2][2]);
            acc[2][3] = fmaf(a2, b.w, acc[2][3]);
            acc[3][0] = fmaf(a3, b.x, acc[3][0]);
            acc[3][1] = fmaf(a3, b.y, acc[3][1]);
            acc[3][2] = fmaf(a3, b.z, acc[3][2]);
            acc[3][3] = fmaf(a3, b.w, acc[3][3]);
        }
        __syncthreads();
    }

#pragma unroll
    for (int i = 0; i < 4; i++) {
        int grow = bm0 + ty * 4 + i;
#pragma unroll
        for (int j = 0; j < 4; j++) {
            int gcol = bn0 + tx * 4 + j;
            if (gcol < N) {
                float v = acc[i][j] + addv[(size_t)(grow & amask) * (size_t)astride + gcol];
                if (ACT == 1) v = (v > 0.f) ? v : 0.01f * v;
                if (STORE == 0) {
                    ((float*)Cout)[(size_t)grow * ldc + gcol] = v;
                } else {
                    // OUTPUT IS FLOAT32 (reference dtype) — row t*128+b -> out[b][t][v]
                    int tt = grow >> 7, bb = grow & 127;
                    ((float*)Cout)[((size_t)(bb * Tz + tt)) * Vz + gcol] = v;
                }
            }
        }
    }
}

extern "C" void kernel_launch(void* const* d_in, const int* in_sizes, int n_in,
                              void* d_out, int out_size, void* d_ws, size_t ws_size,
                              hipStream_t stream) {
    const int* tokens = (const int*)d_in[0];
    const void* features = d_in[1];    // [128,2048]
    const void* embedding = d_in[2];   // [10000,512]
    const void* Wp = d_in[3];          // [2048,1024]
    const void* bp = d_in[4];
    const void* W0[4] = {d_in[5], d_in[7], d_in[9], d_in[11]};   // each [2560,1024]
    const void* b0[4] = {d_in[6], d_in[8], d_in[10], d_in[12]};
    const void* W1[4] = {d_in[13], d_in[15], d_in[17], d_in[19]}; // each [2048,1024]
    const void* b1[4] = {d_in[14], d_in[16], d_in[18], d_in[20]};
    const void* Wout = d_in[21];       // [1024,10000]
    const void* bout = d_in[22];

    char* w = (char*)d_ws;
    size_t cur = 0;
    auto alloc = [&](size_t bytes) {
        size_t o = cur;
        cur += (bytes + 255) & ~(size_t)255;
        return o;
    };
    float* X0f = (float*)(w + alloc((size_t)3200 * Ez * 4));     // [3200][512]
    float* featc = (float*)(w + alloc((size_t)Bz * Fz * 4));     // [128][2048]
    float* feat = (float*)(w + alloc((size_t)Bz * Hz * 4));      // [128][1024]
    float* Sfeat = (float*)(w + alloc((size_t)Bz * 4096 * 4));   // [128][4096]
    float* S0 = (float*)(w + alloc((size_t)3200 * 4096 * 4));    // [3200][4096] 50MB
    // zero-init block (contiguous): h0f, comb1f, c0, c1
    float* h0f = (float*)(w + alloc((size_t)Bz * Hz * 4));
    float* comb1f = (float*)(w + alloc((size_t)Bz * 2048 * 4));
    float* c0 = (float*)(w + alloc((size_t)Bz * Hz * 4));
    float* c1 = (float*)(w + alloc((size_t)Bz * Hz * 4));
    float* hsf = (float*)(w + alloc((size_t)3200 * Hz * 4));     // [3200][1024]
    float* gates = (float*)(w + alloc((size_t)Bz * 4096 * 4));
    float* bp_f = (float*)(w + alloc(1024 * 4));
    float* b0_f = (float*)(w + alloc(4096 * 4));
    float* b1_f = (float*)(w + alloc(4096 * 4));
    float* bout_f = (float*)(w + alloc((size_t)Vz * 4));
    int* dflag = (int*)(w + alloc(256));
    (void)ws_size; (void)in_sizes; (void)n_in; (void)out_size;

    // 0) dtype detect (robustness; expected: f32 path)
    detect_k<<<1, 256, 0, stream>>>((const unsigned short*)embedding, dflag);

    // 1) biases, gather, features, state zero-init
    pack2_k<<<76, 256, 0, stream>>>(bp, b0[0], b0[1], b0[2], b0[3],
                                    b1[0], b1[1], b1[2], b1[3], bout,
                                    bp_f, b0_f, b1_f, bout_f, dflag);
    gatherf_k<<<1600, 256, 0, stream>>>(tokens, embedding, X0f, dflag);
    convf_k<<<1024, 256, 0, stream>>>(features, featc, Bz * Fz, dflag);
    hipMemsetAsync(h0f, 0,
                   (size_t)(Bz * Hz * 4 + Bz * 2048 * 4 + Bz * Hz * 4 + Bz * Hz * 4), stream);

    // 2) feat = leaky_relu(featc @ Wp + bp)   [128,1024] f32
    sgemm_k<0, 1, false><<<dim3(16, 2), 256, 0, stream>>>(
        featc, Fz, Wp, Wp, Wp, Wp, Hz, 0, bp_f, 0, 127, feat, Hz, Bz, Hz, Fz, dflag);

    // 3) Sfeat = feat @ W0[rows 512:1536] + b0   [128,4096] f32
    sgemm_k<0, 0, true><<<dim3(64, 2), 256, 0, stream>>>(
        feat, Hz, W0[0], W0[1], W0[2], W0[3], Hz, 512, b0_f, 0, 127,
        Sfeat, 4096, Bz, 4096, Hz, dflag);

    // 4) S0 = X0 @ W0[rows 0:512] + Sfeat[row&127]   [3200,4096] f32
    sgemm_k<0, 0, true><<<dim3(64, 50), 256, 0, stream>>>(
        X0f, Ez, W0[0], W0[1], W0[2], W0[3], Hz, 0, Sfeat, 4096, 127,
        S0, 4096, 3200, 4096, Ez, dflag);

    // 5) time loop
    for (int t = 0; t < Tz; t++) {
        // gates = h0 @ W0[rows 1536:2560] + S0[t]
        sgemm_k<0, 0, true><<<dim3(64, 2), 256, 0, stream>>>(
            h0f, Hz, W0[0], W0[1], W0[2], W0[3], Hz, 1536,
            S0 + (size_t)t * Bz * 4096, 4096, 127, gates, 4096, Bz, 4096, Hz, dflag);
        cellf_k<<<512, 256, 0, stream>>>(gates, c0, h0f, 1024, comb1f, 2048);
        // gates = [h0n | h1] @ W1 + b1
        sgemm_k<0, 0, true><<<dim3(64, 2), 256, 0, stream>>>(
            comb1f, 2048, W1[0], W1[1], W1[2], W1[3], Hz, 0,
            b1_f, 0, 127, gates, 4096, Bz, 4096, 2048, dflag);
        cellf_k<<<512, 256, 0, stream>>>(gates, c1, hsf + (size_t)t * Bz * Hz, 1024,
                                         comb1f + 1024, 2048);
    }

    // 6) logits = hs @ Wout + bout -> out[b][t][v] FLOAT32
    sgemm_k<2, 0, false><<<dim3(157, 50), 256, 0, stream>>>(
        hsf, Hz, Wout, Wout, Wout, Wout, Vz, 0, bout_f, 0, 127,
        d_out, Vz, 3200, Vz, Hz, dflag);
}